// Round 2
// baseline (565.573 us; speedup 1.0000x reference)
//
#include <hip/hip_runtime.h>
#include <cstdint>

#define D_MODEL 512
#define NUM_HEADS 8
#define D_HEAD 64
#define KNB 16
#define LN_EPS 1e-5f
#define FINF 3.4e38f

__device__ __forceinline__ float wave_reduce_sum(float v) {
  #pragma unroll
  for (int off = 32; off > 0; off >>= 1) v += __shfl_xor(v, off, 64);
  return v;
}

// ---------------------------------------------------------------------------
// Kernel 0: pad positions (B*N,3) -> float4 for vectorized loads in kNN
// ---------------------------------------------------------------------------
__global__ void pad_pos_kernel(const float* __restrict__ pos,
                               float4* __restrict__ posf4, int total) {
  int t = blockIdx.x * blockDim.x + threadIdx.x;
  if (t < total) {
    posf4[t] = make_float4(pos[t * 3], pos[t * 3 + 1], pos[t * 3 + 2], 0.f);
  }
}

// ---------------------------------------------------------------------------
// Kernel 1: kNN — one wave (64 threads) per query point.
// Pass 1: per-lane min over strided candidates; 16th-smallest of the 64 lane
// minima is an upper bound tau on the true 16-NN radius. Pass 2: ballot
// candidates with d <= tau*(1+eps) (eps guards against FMA-contraction
// differences between the two loops) and bubble-insert into a wave-replicated
// sorted top-16. Neighbor order is irrelevant (softmax-weighted sum is
// permutation invariant); self (d==0) is the strict minimum so excluding
// j==n matches idx[:, :, 1:k+1].
// ---------------------------------------------------------------------------
__global__ __launch_bounds__(64) void knn_kernel(const float4* __restrict__ posf4,
                                                 int* __restrict__ idx_out,
                                                 int N) {
  const int q = blockIdx.x;         // 0 .. B*N-1
  const int b = q / N;
  const int n = q - b * N;
  const int lane = threadIdx.x;
  const float4* pb = posf4 + b * N;
  const float4 qp = pb[n];

  // ---- pass 1: per-lane minimum over its strided candidate subset ----
  float lmin = FINF;
  for (int g = 0; g < N; g += 64) {
    const int j = g + lane;
    const float4 p = pb[j];
    const float dx = qp.x - p.x, dy = qp.y - p.y, dz = qp.z - p.z;
    float d = dx * dx + dy * dy + dz * dz;
    if (j == n) d = FINF;
    lmin = fminf(lmin, d);
  }
  // 16th smallest of the 64 lane minima (tie-dedup collapses lanes: tau only
  // grows, still a valid upper bound)
  float cur = lmin;
  float tau = FINF;
  #pragma unroll
  for (int r = 0; r < KNB; ++r) {
    float m = cur;
    #pragma unroll
    for (int off = 32; off > 0; off >>= 1) m = fminf(m, __shfl_xor(m, off, 64));
    tau = m;
    if (cur == m) cur = FINF;
  }
  // relative-epsilon margin: pass-2 recomputation may differ by ~1 ulp
  tau = tau * 1.000002f + 1e-30f;

  // ---- pass 2: collect everything <= tau into a sorted top-16 ----
  float dist[KNB];
  int nidx[KNB];
  #pragma unroll
  for (int t = 0; t < KNB; ++t) { dist[t] = FINF; nidx[t] = -1; }

  for (int g = 0; g < N; g += 64) {
    const int j = g + lane;
    const float4 p = pb[j];
    const float dx = qp.x - p.x, dy = qp.y - p.y, dz = qp.z - p.z;
    const float d = dx * dx + dy * dy + dz * dz;
    const bool pred = (d <= tau) && (j != n);
    unsigned long long mask = __ballot(pred);
    while (mask) {
      const int src = __builtin_ctzll(mask);
      mask &= (mask - 1);
      const float dd = __shfl(d, src, 64);  // wave-uniform
      const int jj = g + src;
      if (dd < dist[KNB - 1]) {             // uniform branch
        float dc = dd;
        int ic = jj;
        #pragma unroll
        for (int t = 0; t < KNB; ++t) {
          const bool sw = dc < dist[t];
          const float od = dist[t];
          const int oi = nidx[t];
          dist[t] = sw ? dc : od;
          nidx[t] = sw ? ic : oi;
          dc = sw ? od : dc;
          ic = sw ? oi : ic;
        }
      }
    }
  }

  // write: lane t writes element t (arrays are wave-replicated).
  // clamp -1 -> 0 as a belt-and-braces guard against downstream faults.
  #pragma unroll
  for (int t = 0; t < KNB; ++t) {
    const int v = nidx[t] < 0 ? 0 : nidx[t];
    if (lane == t) idx_out[q * KNB + t] = v;
  }
}

// ---------------------------------------------------------------------------
// Kernel 2: fp32 SGEMM  C[M,N] = A[M,K] @ B[K,N]
// 128x128 tile, BK=8, 256 threads, 8x8 micro-tile per thread.
// (No fp32 MFMA on CDNA4 -> vector ALU. bf16-split MFMA is the next step.)
// ---------------------------------------------------------------------------
__global__ __launch_bounds__(256) void sgemm128_kernel(const float* __restrict__ A,
                                                       const float* __restrict__ B,
                                                       float* __restrict__ C,
                                                       int M, int N, int K) {
  __shared__ float As[8][128];
  __shared__ float Bs[8][128];
  const int tid = threadIdx.x;
  const int bm = blockIdx.y, bn = blockIdx.x;

  const int arow = tid >> 1;          // 0..127
  const int acol = (tid & 1) << 2;    // 0 or 4
  const int brow = tid >> 5;          // 0..7
  const int bcol = (tid & 31) << 2;   // 0..124
  const int tm = (tid >> 4) << 3;     // micro-tile row base
  const int tn = (tid & 15) << 3;     // micro-tile col base

  const float* Ap = A + (size_t)(bm * 128 + arow) * K + acol;
  const float* Bp = B + (size_t)brow * N + bn * 128 + bcol;

  float acc[8][8];
  #pragma unroll
  for (int i = 0; i < 8; ++i)
    #pragma unroll
    for (int j = 0; j < 8; ++j) acc[i][j] = 0.f;

  for (int k0 = 0; k0 < K; k0 += 8) {
    const float4 av = *(const float4*)(Ap + k0);
    const float4 bv = *(const float4*)(Bp + (size_t)k0 * N);
    As[acol + 0][arow] = av.x;
    As[acol + 1][arow] = av.y;
    As[acol + 2][arow] = av.z;
    As[acol + 3][arow] = av.w;
    *(float4*)&Bs[brow][bcol] = bv;
    __syncthreads();
    #pragma unroll
    for (int kk = 0; kk < 8; ++kk) {
      float a[8], bb[8];
      *(float4*)&a[0]  = *(const float4*)&As[kk][tm];
      *(float4*)&a[4]  = *(const float4*)&As[kk][tm + 4];
      *(float4*)&bb[0] = *(const float4*)&Bs[kk][tn];
      *(float4*)&bb[4] = *(const float4*)&Bs[kk][tn + 4];
      #pragma unroll
      for (int i = 0; i < 8; ++i)
        #pragma unroll
        for (int j = 0; j < 8; ++j) acc[i][j] += a[i] * bb[j];
    }
    __syncthreads();
  }

  float* Cp = C + (size_t)(bm * 128 + tm) * N + bn * 128 + tn;
  #pragma unroll
  for (int i = 0; i < 8; ++i) {
    *(float4*)(Cp + (size_t)i * N)     = *(const float4*)&acc[i][0];
    *(float4*)(Cp + (size_t)i * N + 4) = *(const float4*)&acc[i][4];
  }
}

// ---------------------------------------------------------------------------
// Kernel 3: local attention — one wave per (query, head).
// pe: tile(pe,4)[..., :64] == first 64 cols of rel_pos @ Wpos + bpos,
// shared across heads. scores = q.(k_j + pe)/temp -> softmax(16) -> sum w*v.
// NOTE: att is written IN-PLACE into Q: wave (n,h) reads exactly
// Q[n, h*64+lane] (before the write, same wave) and no other wave touches
// that element -> race-free, saves a 16 MB buffer.
// ---------------------------------------------------------------------------
__global__ __launch_bounds__(256) void attn_kernel(float* __restrict__ Q,
                                                   const float* __restrict__ Kb,
                                                   const float* __restrict__ Vb,
                                                   const int* __restrict__ idx,
                                                   const float* __restrict__ pos,
                                                   const float* __restrict__ Wpos,
                                                   const float* __restrict__ bpos,
                                                   const float* __restrict__ temperature,
                                                   int N) {
  const int wid = blockIdx.x * 4 + (threadIdx.x >> 6);
  const int lane = threadIdx.x & 63;
  const int h = wid & (NUM_HEADS - 1);
  const int n_glob = wid >> 3;        // 0 .. B*N-1
  const int b = n_glob / N;
  const int n = n_glob - b * N;

  const float inv_t = 1.0f / temperature[0];
  const float qv = Q[(size_t)n_glob * D_MODEL + h * D_HEAD + lane];
  const float wp0 = Wpos[lane];
  const float wp1 = Wpos[128 + lane];
  const float wp2 = Wpos[256 + lane];
  const float bp = bpos[lane];
  const float px = pos[(size_t)(b * N + n) * 3 + 0];
  const float py = pos[(size_t)(b * N + n) * 3 + 1];
  const float pz = pos[(size_t)(b * N + n) * 3 + 2];
  const int* ip = idx + (size_t)n_glob * KNB;

  float sc[KNB];
  #pragma unroll
  for (int k = 0; k < KNB; ++k) {
    const int j = ip[k];
    const size_t row = (size_t)(b * N + j) * D_MODEL + h * D_HEAD + lane;
    const float kk = Kb[row];
    const float rx = px - pos[(size_t)(b * N + j) * 3 + 0];
    const float ry = py - pos[(size_t)(b * N + j) * 3 + 1];
    const float rz = pz - pos[(size_t)(b * N + j) * 3 + 2];
    const float pe = rx * wp0 + ry * wp1 + rz * wp2 + bp;
    sc[k] = wave_reduce_sum(qv * (kk + pe)) * inv_t;
  }

  float m = sc[0];
  #pragma unroll
  for (int k = 1; k < KNB; ++k) m = fmaxf(m, sc[k]);
  float s = 0.f;
  #pragma unroll
  for (int k = 0; k < KNB; ++k) { sc[k] = expf(sc[k] - m); s += sc[k]; }
  const float inv_s = 1.f / s;

  float acc = 0.f;
  #pragma unroll
  for (int k = 0; k < KNB; ++k) {
    const int j = ip[k];
    acc += sc[k] * Vb[(size_t)(b * N + j) * D_MODEL + h * D_HEAD + lane];
  }
  Q[(size_t)n_glob * D_MODEL + h * D_HEAD + lane] = acc * inv_s;
}

// ---------------------------------------------------------------------------
// Kernel 4: out = LayerNorm(proj + bo + features) * gamma + beta
// one wave per row of 512.
// ---------------------------------------------------------------------------
__global__ __launch_bounds__(256) void ln_kernel(const float* __restrict__ proj,
                                                 const float* __restrict__ feat,
                                                 const float* __restrict__ bo,
                                                 const float* __restrict__ gamma,
                                                 const float* __restrict__ beta,
                                                 float* __restrict__ out) {
  const int row = blockIdx.x * 4 + (threadIdx.x >> 6);
  const int lane = threadIdx.x & 63;
  const float* pr = proj + (size_t)row * D_MODEL;
  const float* fr = feat + (size_t)row * D_MODEL;

  float x[8];
  #pragma unroll
  for (int u = 0; u < 2; ++u) {
    const int c = u * 256 + lane * 4;
    const float4 p = *(const float4*)(pr + c);
    const float4 f = *(const float4*)(fr + c);
    const float4 bb = *(const float4*)(bo + c);
    x[u * 4 + 0] = p.x + bb.x + f.x;
    x[u * 4 + 1] = p.y + bb.y + f.y;
    x[u * 4 + 2] = p.z + bb.z + f.z;
    x[u * 4 + 3] = p.w + bb.w + f.w;
  }
  float sum = 0.f, sumsq = 0.f;
  #pragma unroll
  for (int i = 0; i < 8; ++i) { sum += x[i]; sumsq += x[i] * x[i]; }
  sum = wave_reduce_sum(sum);
  sumsq = wave_reduce_sum(sumsq);
  const float mu = sum * (1.f / D_MODEL);
  const float var = sumsq * (1.f / D_MODEL) - mu * mu;
  const float rstd = rsqrtf(var + LN_EPS);

  #pragma unroll
  for (int u = 0; u < 2; ++u) {
    const int c = u * 256 + lane * 4;
    const float4 g = *(const float4*)(gamma + c);
    const float4 bt = *(const float4*)(beta + c);
    float4 o;
    o.x = (x[u * 4 + 0] - mu) * rstd * g.x + bt.x;
    o.y = (x[u * 4 + 1] - mu) * rstd * g.y + bt.y;
    o.z = (x[u * 4 + 2] - mu) * rstd * g.z + bt.z;
    o.w = (x[u * 4 + 3] - mu) * rstd * g.w + bt.w;
    *(float4*)(out + (size_t)row * D_MODEL + c) = o;
  }
}

// ---------------------------------------------------------------------------
extern "C" void kernel_launch(void* const* d_in, const int* in_sizes, int n_in,
                              void* d_out, int out_size, void* d_ws, size_t ws_size,
                              hipStream_t stream) {
  const float* positions = (const float*)d_in[0];
  const float* features  = (const float*)d_in[1];
  // d_in[2] = k_neighbors (hardcoded 16)
  const float* Wq   = (const float*)d_in[3];
  const float* Wk   = (const float*)d_in[4];
  const float* Wv   = (const float*)d_in[5];
  const float* Wo   = (const float*)d_in[6];
  const float* bo   = (const float*)d_in[7];
  const float* Wpos = (const float*)d_in[8];
  const float* bpos = (const float*)d_in[9];
  const float* temp = (const float*)d_in[10];
  const float* gamma = (const float*)d_in[11];
  const float* beta  = (const float*)d_in[12];

  const int B = 2, N = 4096;
  const int BN = B * N;

  // workspace layout (~32.6 MB): posf4 | idx | Q | K
  //   V lives in d_out (dead before LN overwrites it)
  //   att is computed in-place into Q
  //   proj reuses K (dead after attention)
  char* w = (char*)d_ws;
  float4* posf4 = (float4*)w;            w += (size_t)BN * sizeof(float4);
  int*    idxb  = (int*)w;               w += (size_t)BN * KNB * sizeof(int);
  float*  Qb    = (float*)w;             w += (size_t)BN * D_MODEL * sizeof(float);
  float*  Kbuf  = (float*)w;             w += (size_t)BN * D_MODEL * sizeof(float);
  float*  Vbuf  = (float*)d_out;   // scratch until ln_kernel overwrites d_out
  float*  projb = Kbuf;            // K dead after attention

  pad_pos_kernel<<<(BN + 255) / 256, 256, 0, stream>>>(positions, posf4, BN);
  knn_kernel<<<BN, 64, 0, stream>>>(posf4, idxb, N);

  dim3 g(D_MODEL / 128, BN / 128);
  sgemm128_kernel<<<g, 256, 0, stream>>>(features, Wq, Qb,   BN, D_MODEL, D_MODEL);
  sgemm128_kernel<<<g, 256, 0, stream>>>(features, Wk, Kbuf, BN, D_MODEL, D_MODEL);
  sgemm128_kernel<<<g, 256, 0, stream>>>(features, Wv, Vbuf, BN, D_MODEL, D_MODEL);

  attn_kernel<<<BN * NUM_HEADS / 4, 256, 0, stream>>>(Qb, Kbuf, Vbuf, idxb,
                                                      positions, Wpos, bpos,
                                                      temp, N);

  sgemm128_kernel<<<g, 256, 0, stream>>>(Qb, Wo, projb, BN, D_MODEL, D_MODEL);

  ln_kernel<<<BN / 4, 256, 0, stream>>>(projb, features, bo, gamma, beta,
                                        (float*)d_out);
}

// Round 3
// 346.182 us; speedup vs baseline: 1.6337x; 1.6337x over previous
//
#include <hip/hip_runtime.h>
#include <cstdint>

#define D_MODEL 512
#define NUM_HEADS 8
#define D_HEAD 64
#define KNB 16
#define LN_EPS 1e-5f
#define FINF 3.4e38f

typedef __bf16 bf16x8v __attribute__((ext_vector_type(8)));
typedef float f32x4v __attribute__((ext_vector_type(4)));
typedef int i32x4 __attribute__((ext_vector_type(4)));
typedef const __attribute__((address_space(1))) unsigned int* gptr_t;
typedef __attribute__((address_space(3))) unsigned int* lptr_t;

__device__ __forceinline__ float wave_reduce_sum(float v) {
  #pragma unroll
  for (int off = 32; off > 0; off >>= 1) v += __shfl_xor(v, off, 64);
  return v;
}

// bf16 helpers (bit-level, round-to-nearest-even; avoids hip_bf16 API drift)
__device__ __forceinline__ unsigned short f2bf(float x) {
  unsigned int u = __float_as_uint(x);
  u = (u + 0x7fffu + ((u >> 16) & 1u)) >> 16;
  return (unsigned short)u;
}
__device__ __forceinline__ float bf2f(unsigned short h) {
  return __uint_as_float(((unsigned int)h) << 16);
}

// ---------------------------------------------------------------------------
// Kernel 0: pad positions (B*N,3) -> float4
// ---------------------------------------------------------------------------
__global__ void pad_pos_kernel(const float* __restrict__ pos,
                               float4* __restrict__ posf4, int total) {
  int t = blockIdx.x * blockDim.x + threadIdx.x;
  if (t < total) {
    posf4[t] = make_float4(pos[t * 3], pos[t * 3 + 1], pos[t * 3 + 2], 0.f);
  }
}

// ---------------------------------------------------------------------------
// Kernel 1: kNN — one wave per query (unchanged from Round 2; passed).
// ---------------------------------------------------------------------------
__global__ __launch_bounds__(64) void knn_kernel(const float4* __restrict__ posf4,
                                                 int* __restrict__ idx_out,
                                                 int N) {
  const int q = blockIdx.x;
  const int b = q / N;
  const int n = q - b * N;
  const int lane = threadIdx.x;
  const float4* pb = posf4 + b * N;
  const float4 qp = pb[n];

  float lmin = FINF;
  for (int g = 0; g < N; g += 64) {
    const int j = g + lane;
    const float4 p = pb[j];
    const float dx = qp.x - p.x, dy = qp.y - p.y, dz = qp.z - p.z;
    float d = dx * dx + dy * dy + dz * dz;
    if (j == n) d = FINF;
    lmin = fminf(lmin, d);
  }
  float cur = lmin;
  float tau = FINF;
  #pragma unroll
  for (int r = 0; r < KNB; ++r) {
    float m = cur;
    #pragma unroll
    for (int off = 32; off > 0; off >>= 1) m = fminf(m, __shfl_xor(m, off, 64));
    tau = m;
    if (cur == m) cur = FINF;
  }
  tau = tau * 1.000002f + 1e-30f;

  float dist[KNB];
  int nidx[KNB];
  #pragma unroll
  for (int t = 0; t < KNB; ++t) { dist[t] = FINF; nidx[t] = -1; }

  for (int g = 0; g < N; g += 64) {
    const int j = g + lane;
    const float4 p = pb[j];
    const float dx = qp.x - p.x, dy = qp.y - p.y, dz = qp.z - p.z;
    const float d = dx * dx + dy * dy + dz * dz;
    const bool pred = (d <= tau) && (j != n);
    unsigned long long mask = __ballot(pred);
    while (mask) {
      const int src = __builtin_ctzll(mask);
      mask &= (mask - 1);
      const float dd = __shfl(d, src, 64);
      const int jj = g + src;
      if (dd < dist[KNB - 1]) {
        float dc = dd;
        int ic = jj;
        #pragma unroll
        for (int t = 0; t < KNB; ++t) {
          const bool sw = dc < dist[t];
          const float od = dist[t];
          const int oi = nidx[t];
          dist[t] = sw ? dc : od;
          nidx[t] = sw ? ic : oi;
          dc = sw ? od : dc;
          ic = sw ? oi : ic;
        }
      }
    }
  }
  #pragma unroll
  for (int t = 0; t < KNB; ++t) {
    const int v = nidx[t] < 0 ? 0 : nidx[t];
    if (lane == t) idx_out[q * KNB + t] = v;
  }
}

// ---------------------------------------------------------------------------
// Kernel 2a: features fp32 MxD -> A' bf16 Mx1024 as [hi(512) | lo(512)]
// ---------------------------------------------------------------------------
__global__ __launch_bounds__(256) void conv_feat_kernel(const float* __restrict__ src,
                                                        unsigned short* __restrict__ dst,
                                                        int total4) {
  const int t = blockIdx.x * blockDim.x + threadIdx.x;
  if (t >= total4) return;
  const int f = t * 4;
  const int row = f >> 9;
  const int col = f & 511;
  const float4 v = *(const float4*)(src + f);
  ushort4 h, l;
  h.x = f2bf(v.x); l.x = f2bf(v.x - bf2f(h.x));
  h.y = f2bf(v.y); l.y = f2bf(v.y - bf2f(h.y));
  h.z = f2bf(v.z); l.z = f2bf(v.z - bf2f(h.z));
  h.w = f2bf(v.w); l.w = f2bf(v.w - bf2f(h.w));
  *(ushort4*)(dst + (size_t)row * 1024 + col) = h;
  *(ushort4*)(dst + (size_t)row * 1024 + 512 + col) = l;
}

// ---------------------------------------------------------------------------
// Kernel 2b: weights (512x512 fp32, W[k][n]) -> transposed split bf16
// Bt_hi[n][k], Bt_lo[n][k].  4 weights in one launch:
// wsel 0..2 -> rows wsel*512.. of qkv buffers; wsel 3 -> o buffers.
// ---------------------------------------------------------------------------
__global__ __launch_bounds__(256) void conv_w_kernel(const float* __restrict__ Wq,
                                                     const float* __restrict__ Wk,
                                                     const float* __restrict__ Wv,
                                                     const float* __restrict__ Wo,
                                                     unsigned short* __restrict__ BhQKV,
                                                     unsigned short* __restrict__ BlQKV,
                                                     unsigned short* __restrict__ BhO,
                                                     unsigned short* __restrict__ BlO) {
  const int wsel = blockIdx.x >> 10;                 // 1024 blocks per weight
  const int i = ((blockIdx.x & 1023) << 8) + threadIdx.x;  // 0 .. 262143
  const int n = i >> 9;
  const int k = i & 511;
  const float* src = wsel == 0 ? Wq : wsel == 1 ? Wk : wsel == 2 ? Wv : Wo;
  unsigned short* dh = wsel < 3 ? BhQKV + (size_t)(wsel * 512 + n) * 512
                                : BhO + (size_t)n * 512;
  unsigned short* dl = wsel < 3 ? BlQKV + (size_t)(wsel * 512 + n) * 512
                                : BlO + (size_t)n * 512;
  const float w = src[(size_t)k * 512 + n];
  const unsigned short h = f2bf(w);
  dh[k] = h;
  dl[k] = f2bf(w - bf2f(h));
}

// ---------------------------------------------------------------------------
// Kernel 3: split-bf16 MFMA GEMM.  C = A_f32 @ B_f32 computed as
//   loop1 (K=1024): [A_hi|A_lo] x B_hi(k mod 512)  -> a * hi_b
//   loop2 (K=512):  A_hi x B_lo                    -> hi_a * lo_b
// (lo*lo dropped, ~2^-16 relative).  128x128 tile, 256 thr = 4 waves,
// each wave 64x64 via 4x4 of 16x16x32 MFMA.  global_load_lds width 16.
// Output column split: bn>>2 selects C0/C1/C2 (M x 512 each).
// ---------------------------------------------------------------------------
__global__ __launch_bounds__(256) void gemm_split_kernel(
    const unsigned short* __restrict__ A,    // M x 1024  [hi|lo]
    const unsigned short* __restrict__ Bh,   // Ncols x 512
    const unsigned short* __restrict__ Bl,   // Ncols x 512
    float* __restrict__ C0, float* __restrict__ C1, float* __restrict__ C2) {
  __shared__ unsigned short lds[8192];       // As 128x32 | Bs 128x32
  unsigned short* As = lds;
  unsigned short* Bs = lds + 4096;

  const int tid = threadIdx.x;
  const int wid = tid >> 6;
  const int lane = tid & 63;
  const int lm = lane & 15;
  const int kq = lane >> 4;
  const int wr = wid >> 1;                   // wave m-half
  const int wc = wid & 1;                    // wave n-half
  const int bm = blockIdx.y, bn = blockIdx.x;
  const int rowA0 = bm * 128;
  const int rowB0 = bn * 128;

  f32x4v acc[4][4];
  #pragma unroll
  for (int mi = 0; mi < 4; ++mi)
    #pragma unroll
    for (int ni = 0; ni < 4; ++ni) {
      f32x4v z = {0.f, 0.f, 0.f, 0.f};
      acc[mi][ni] = z;
    }

  auto kloop = [&](const unsigned short* __restrict__ Bsrc, int kmax) {
    for (int k0 = 0; k0 < kmax; k0 += 32) {
      #pragma unroll
      for (int i = 0; i < 2; ++i) {
        const int e = wid * 128 + i * 64 + lane;   // 16B chunk index, 0..511
        const int row = e >> 2;
        const int kc = (e & 3) << 3;
        const unsigned short* ga = A + (size_t)(rowA0 + row) * 1024 + k0 + kc;
        const unsigned short* gb = Bsrc + (size_t)(rowB0 + row) * 512 + (k0 & 511) + kc;
        // LDS dest is wave-uniform base + lane*16
        __builtin_amdgcn_global_load_lds((gptr_t)ga,
            (lptr_t)(As + (size_t)(wid * 128 + i * 64) * 8), 16, 0, 0);
        __builtin_amdgcn_global_load_lds((gptr_t)gb,
            (lptr_t)(Bs + (size_t)(wid * 128 + i * 64) * 8), 16, 0, 0);
      }
      __syncthreads();
      i32x4 araw[4], braw[4];
      #pragma unroll
      for (int mi = 0; mi < 4; ++mi)
        araw[mi] = *(const i32x4*)(As + (size_t)(wr * 64 + mi * 16 + lm) * 32 + kq * 8);
      #pragma unroll
      for (int ni = 0; ni < 4; ++ni)
        braw[ni] = *(const i32x4*)(Bs + (size_t)(wc * 64 + ni * 16 + lm) * 32 + kq * 8);
      #pragma unroll
      for (int mi = 0; mi < 4; ++mi)
        #pragma unroll
        for (int ni = 0; ni < 4; ++ni)
          acc[mi][ni] = __builtin_amdgcn_mfma_f32_16x16x32_bf16(
              __builtin_bit_cast(bf16x8v, araw[mi]),
              __builtin_bit_cast(bf16x8v, braw[ni]), acc[mi][ni], 0, 0, 0);
      __syncthreads();
    }
  };
  kloop(Bh, 1024);   // a * hi_b
  kloop(Bl, 512);    // hi_a * lo_b

  const int sel = bn >> 2;
  float* __restrict__ Cb = sel == 0 ? C0 : sel == 1 ? C1 : C2;
  const int r0 = bm * 128 + wr * 64;
  const int c0 = ((bn & 3) << 7) + wc * 64;
  // C/D layout: col = lane&15, row = (lane>>4)*4 + reg   [m89/m91]
  #pragma unroll
  for (int mi = 0; mi < 4; ++mi)
    #pragma unroll
    for (int ni = 0; ni < 4; ++ni) {
      float* Cp = Cb + (size_t)(r0 + mi * 16 + kq * 4) * 512 + c0 + ni * 16 + lm;
      #pragma unroll
      for (int r = 0; r < 4; ++r) Cp[(size_t)r * 512] = acc[mi][ni][r];
    }
}

// ---------------------------------------------------------------------------
// Kernel 4: local attention — one wave per (query, head).  Reads fp32 Q/K/V,
// writes att directly as split bf16 into A' (the features' split buffer,
// dead after the QKV GEMM) so the Wo GEMM needs no extra conversion pass.
// ---------------------------------------------------------------------------
__global__ __launch_bounds__(256) void attn_kernel(const float* __restrict__ Q,
                                                   const float* __restrict__ Kb,
                                                   const float* __restrict__ Vb,
                                                   const int* __restrict__ idx,
                                                   const float* __restrict__ pos,
                                                   const float* __restrict__ Wpos,
                                                   const float* __restrict__ bpos,
                                                   const float* __restrict__ temperature,
                                                   unsigned short* __restrict__ Aout,
                                                   int N) {
  const int wid = blockIdx.x * 4 + (threadIdx.x >> 6);
  const int lane = threadIdx.x & 63;
  const int h = wid & (NUM_HEADS - 1);
  const int n_glob = wid >> 3;
  const int b = n_glob / N;
  const int n = n_glob - b * N;

  const float inv_t = 1.0f / temperature[0];
  const float qv = Q[(size_t)n_glob * D_MODEL + h * D_HEAD + lane];
  const float wp0 = Wpos[lane];
  const float wp1 = Wpos[128 + lane];
  const float wp2 = Wpos[256 + lane];
  const float bp = bpos[lane];
  const float px = pos[(size_t)(b * N + n) * 3 + 0];
  const float py = pos[(size_t)(b * N + n) * 3 + 1];
  const float pz = pos[(size_t)(b * N + n) * 3 + 2];
  const int* ip = idx + (size_t)n_glob * KNB;

  float sc[KNB];
  #pragma unroll
  for (int k = 0; k < KNB; ++k) {
    const int j = ip[k];
    const size_t row = (size_t)(b * N + j) * D_MODEL + h * D_HEAD + lane;
    const float kk = Kb[row];
    const float rx = px - pos[(size_t)(b * N + j) * 3 + 0];
    const float ry = py - pos[(size_t)(b * N + j) * 3 + 1];
    const float rz = pz - pos[(size_t)(b * N + j) * 3 + 2];
    const float pe = rx * wp0 + ry * wp1 + rz * wp2 + bp;
    sc[k] = wave_reduce_sum(qv * (kk + pe)) * inv_t;
  }

  float m = sc[0];
  #pragma unroll
  for (int k = 1; k < KNB; ++k) m = fmaxf(m, sc[k]);
  float s = 0.f;
  #pragma unroll
  for (int k = 0; k < KNB; ++k) { sc[k] = expf(sc[k] - m); s += sc[k]; }
  const float inv_s = 1.f / s;

  float acc = 0.f;
  #pragma unroll
  for (int k = 0; k < KNB; ++k) {
    const int j = ip[k];
    acc += sc[k] * Vb[(size_t)(b * N + j) * D_MODEL + h * D_HEAD + lane];
  }
  const float a = acc * inv_s;
  const unsigned short hi = f2bf(a);
  const unsigned short lo = f2bf(a - bf2f(hi));
  Aout[(size_t)n_glob * 1024 + h * D_HEAD + lane] = hi;
  Aout[(size_t)n_glob * 1024 + 512 + h * D_HEAD + lane] = lo;
}

// ---------------------------------------------------------------------------
// Kernel 5: out = LayerNorm(proj + bo + features) * gamma + beta
// ---------------------------------------------------------------------------
__global__ __launch_bounds__(256) void ln_kernel(const float* __restrict__ proj,
                                                 const float* __restrict__ feat,
                                                 const float* __restrict__ bo,
                                                 const float* __restrict__ gamma,
                                                 const float* __restrict__ beta,
                                                 float* __restrict__ out) {
  const int row = blockIdx.x * 4 + (threadIdx.x >> 6);
  const int lane = threadIdx.x & 63;
  const float* pr = proj + (size_t)row * D_MODEL;
  const float* fr = feat + (size_t)row * D_MODEL;

  float x[8];
  #pragma unroll
  for (int u = 0; u < 2; ++u) {
    const int c = u * 256 + lane * 4;
    const float4 p = *(const float4*)(pr + c);
    const float4 f = *(const float4*)(fr + c);
    const float4 bb = *(const float4*)(bo + c);
    x[u * 4 + 0] = p.x + bb.x + f.x;
    x[u * 4 + 1] = p.y + bb.y + f.y;
    x[u * 4 + 2] = p.z + bb.z + f.z;
    x[u * 4 + 3] = p.w + bb.w + f.w;
  }
  float sum = 0.f, sumsq = 0.f;
  #pragma unroll
  for (int i = 0; i < 8; ++i) { sum += x[i]; sumsq += x[i] * x[i]; }
  sum = wave_reduce_sum(sum);
  sumsq = wave_reduce_sum(sumsq);
  const float mu = sum * (1.f / D_MODEL);
  const float var = sumsq * (1.f / D_MODEL) - mu * mu;
  const float rstd = rsqrtf(var + LN_EPS);

  #pragma unroll
  for (int u = 0; u < 2; ++u) {
    const int c = u * 256 + lane * 4;
    const float4 g = *(const float4*)(gamma + c);
    const float4 bt = *(const float4*)(beta + c);
    float4 o;
    o.x = (x[u * 4 + 0] - mu) * rstd * g.x + bt.x;
    o.y = (x[u * 4 + 1] - mu) * rstd * g.y + bt.y;
    o.z = (x[u * 4 + 2] - mu) * rstd * g.z + bt.z;
    o.w = (x[u * 4 + 3] - mu) * rstd * g.w + bt.w;
    *(float4*)(out + (size_t)row * D_MODEL + c) = o;
  }
}

// ---------------------------------------------------------------------------
extern "C" void kernel_launch(void* const* d_in, const int* in_sizes, int n_in,
                              void* d_out, int out_size, void* d_ws, size_t ws_size,
                              hipStream_t stream) {
  const float* positions = (const float*)d_in[0];
  const float* features  = (const float*)d_in[1];
  const float* Wq   = (const float*)d_in[3];
  const float* Wk   = (const float*)d_in[4];
  const float* Wv   = (const float*)d_in[5];
  const float* Wo   = (const float*)d_in[6];
  const float* bo   = (const float*)d_in[7];
  const float* Wpos = (const float*)d_in[8];
  const float* bpos = (const float*)d_in[9];
  const float* temp = (const float*)d_in[10];
  const float* gamma = (const float*)d_in[11];
  const float* beta  = (const float*)d_in[12];

  const int B = 2, N = 4096;
  const int BN = B * N;       // 8192 rows

  // workspace (~52.6 MB):
  //   posf4 | idx | A'(Mx1024 bf16) | BhQKV | BlQKV | BhO | BlO | Q | K
  //   V lives in d_out (dead before LN overwrites it)
  //   att -> split bf16 directly into A'; proj reuses K
  char* w = (char*)d_ws;
  float4* posf4 = (float4*)w;              w += (size_t)BN * sizeof(float4);
  int*    idxb  = (int*)w;                 w += (size_t)BN * KNB * sizeof(int);
  unsigned short* Abuf = (unsigned short*)w; w += (size_t)BN * 1024 * 2;
  unsigned short* BhQKV = (unsigned short*)w; w += (size_t)1536 * 512 * 2;
  unsigned short* BlQKV = (unsigned short*)w; w += (size_t)1536 * 512 * 2;
  unsigned short* BhO = (unsigned short*)w;   w += (size_t)512 * 512 * 2;
  unsigned short* BlO = (unsigned short*)w;   w += (size_t)512 * 512 * 2;
  float* Qb   = (float*)w;                 w += (size_t)BN * D_MODEL * sizeof(float);
  float* Kbuf = (float*)w;                 w += (size_t)BN * D_MODEL * sizeof(float);
  float* Vbuf = (float*)d_out;
  float* projb = Kbuf;

  pad_pos_kernel<<<(BN + 255) / 256, 256, 0, stream>>>(positions, posf4, BN);
  knn_kernel<<<BN, 64, 0, stream>>>(posf4, idxb, N);

  conv_feat_kernel<<<(BN * D_MODEL / 4 + 255) / 256, 256, 0, stream>>>(
      features, Abuf, BN * D_MODEL / 4);
  conv_w_kernel<<<4096, 256, 0, stream>>>(Wq, Wk, Wv, Wo, BhQKV, BlQKV, BhO, BlO);

  // fused QKV: N=1536 -> 12 x 64 = 768 blocks (3 blocks/CU)
  gemm_split_kernel<<<dim3(12, BN / 128), 256, 0, stream>>>(
      Abuf, BhQKV, BlQKV, Qb, Kbuf, Vbuf);

  attn_kernel<<<BN * NUM_HEADS / 4, 256, 0, stream>>>(Qb, Kbuf, Vbuf, idxb,
                                                      positions, Wpos, bpos,
                                                      temp, Abuf, N);

  // output projection: N=512 -> 4 x 64 = 256 blocks
  gemm_split_kernel<<<dim3(4, BN / 128), 256, 0, stream>>>(
      Abuf, BhO, BlO, projb, projb, projb);

  ln_kernel<<<BN / 4, 256, 0, stream>>>(projb, features, bo, gamma, beta,
                                        (float*)d_out);
}

// Round 4
// 343.599 us; speedup vs baseline: 1.6460x; 1.0075x over previous
//
#include <hip/hip_runtime.h>
#include <cstdint>

#define D_MODEL 512
#define NUM_HEADS 8
#define D_HEAD 64
#define KNB 16
#define LN_EPS 1e-5f
#define FINF 3.4e38f

typedef __bf16 bf16x8v __attribute__((ext_vector_type(8)));
typedef float f32x4v __attribute__((ext_vector_type(4)));
typedef int i32x4 __attribute__((ext_vector_type(4)));
typedef const __attribute__((address_space(1))) unsigned int* gptr_t;
typedef __attribute__((address_space(3))) unsigned int* lptr_t;

__device__ __forceinline__ float wave_reduce_sum(float v) {
  #pragma unroll
  for (int off = 32; off > 0; off >>= 1) v += __shfl_xor(v, off, 64);
  return v;
}

// bf16 helpers (bit-level, round-to-nearest-even)
__device__ __forceinline__ unsigned short f2bf(float x) {
  unsigned int u = __float_as_uint(x);
  u = (u + 0x7fffu + ((u >> 16) & 1u)) >> 16;
  return (unsigned short)u;
}
__device__ __forceinline__ float bf2f(unsigned short h) {
  return __uint_as_float(((unsigned int)h) << 16);
}

// ---------------------------------------------------------------------------
// Kernel 0: pad positions (B*N,3) -> float4
// ---------------------------------------------------------------------------
__global__ void pad_pos_kernel(const float* __restrict__ pos,
                               float4* __restrict__ posf4, int total) {
  int t = blockIdx.x * blockDim.x + threadIdx.x;
  if (t < total) {
    posf4[t] = make_float4(pos[t * 3], pos[t * 3 + 1], pos[t * 3 + 2], 0.f);
  }
}

// ---------------------------------------------------------------------------
// Kernel 1: kNN — one wave per query (unchanged; passed twice).
// ---------------------------------------------------------------------------
__global__ __launch_bounds__(64) void knn_kernel(const float4* __restrict__ posf4,
                                                 int* __restrict__ idx_out,
                                                 int N) {
  const int q = blockIdx.x;
  const int b = q / N;
  const int n = q - b * N;
  const int lane = threadIdx.x;
  const float4* pb = posf4 + b * N;
  const float4 qp = pb[n];

  float lmin = FINF;
  for (int g = 0; g < N; g += 64) {
    const int j = g + lane;
    const float4 p = pb[j];
    const float dx = qp.x - p.x, dy = qp.y - p.y, dz = qp.z - p.z;
    float d = dx * dx + dy * dy + dz * dz;
    if (j == n) d = FINF;
    lmin = fminf(lmin, d);
  }
  float cur = lmin;
  float tau = FINF;
  #pragma unroll
  for (int r = 0; r < KNB; ++r) {
    float m = cur;
    #pragma unroll
    for (int off = 32; off > 0; off >>= 1) m = fminf(m, __shfl_xor(m, off, 64));
    tau = m;
    if (cur == m) cur = FINF;
  }
  tau = tau * 1.000002f + 1e-30f;

  float dist[KNB];
  int nidx[KNB];
  #pragma unroll
  for (int t = 0; t < KNB; ++t) { dist[t] = FINF; nidx[t] = -1; }

  for (int g = 0; g < N; g += 64) {
    const int j = g + lane;
    const float4 p = pb[j];
    const float dx = qp.x - p.x, dy = qp.y - p.y, dz = qp.z - p.z;
    const float d = dx * dx + dy * dy + dz * dz;
    const bool pred = (d <= tau) && (j != n);
    unsigned long long mask = __ballot(pred);
    while (mask) {
      const int src = __builtin_ctzll(mask);
      mask &= (mask - 1);
      const float dd = __shfl(d, src, 64);
      const int jj = g + src;
      if (dd < dist[KNB - 1]) {
        float dc = dd;
        int ic = jj;
        #pragma unroll
        for (int t = 0; t < KNB; ++t) {
          const bool sw = dc < dist[t];
          const float od = dist[t];
          const int oi = nidx[t];
          dist[t] = sw ? dc : od;
          nidx[t] = sw ? ic : oi;
          dc = sw ? od : dc;
          ic = sw ? oi : ic;
        }
      }
    }
  }
  #pragma unroll
  for (int t = 0; t < KNB; ++t) {
    const int v = nidx[t] < 0 ? 0 : nidx[t];
    if (lane == t) idx_out[q * KNB + t] = v;
  }
}

// ---------------------------------------------------------------------------
// Kernel 2a: features fp32 MxD -> A' bf16 Mx1024 as [hi(512) | lo(512)]
// ---------------------------------------------------------------------------
__global__ __launch_bounds__(256) void conv_feat_kernel(const float* __restrict__ src,
                                                        unsigned short* __restrict__ dst,
                                                        int total4) {
  const int t = blockIdx.x * blockDim.x + threadIdx.x;
  if (t >= total4) return;
  const int f = t * 4;
  const int row = f >> 9;
  const int col = f & 511;
  const float4 v = *(const float4*)(src + f);
  ushort4 h, l;
  h.x = f2bf(v.x); l.x = f2bf(v.x - bf2f(h.x));
  h.y = f2bf(v.y); l.y = f2bf(v.y - bf2f(h.y));
  h.z = f2bf(v.z); l.z = f2bf(v.z - bf2f(h.z));
  h.w = f2bf(v.w); l.w = f2bf(v.w - bf2f(h.w));
  *(ushort4*)(dst + (size_t)row * 1024 + col) = h;
  *(ushort4*)(dst + (size_t)row * 1024 + 512 + col) = l;
}

// ---------------------------------------------------------------------------
// Kernel 2b: weights (512x512 fp32, W[k][n]) -> transposed split bf16
// ---------------------------------------------------------------------------
__global__ __launch_bounds__(256) void conv_w_kernel(const float* __restrict__ Wq,
                                                     const float* __restrict__ Wk,
                                                     const float* __restrict__ Wv,
                                                     const float* __restrict__ Wo,
                                                     unsigned short* __restrict__ BhQKV,
                                                     unsigned short* __restrict__ BlQKV,
                                                     unsigned short* __restrict__ BhO,
                                                     unsigned short* __restrict__ BlO) {
  const int wsel = blockIdx.x >> 10;
  const int i = ((blockIdx.x & 1023) << 8) + threadIdx.x;
  const int n = i >> 9;
  const int k = i & 511;
  const float* src = wsel == 0 ? Wq : wsel == 1 ? Wk : wsel == 2 ? Wv : Wo;
  unsigned short* dh = wsel < 3 ? BhQKV + (size_t)(wsel * 512 + n) * 512
                                : BhO + (size_t)n * 512;
  unsigned short* dl = wsel < 3 ? BlQKV + (size_t)(wsel * 512 + n) * 512
                                : BlO + (size_t)n * 512;
  const float w = src[(size_t)k * 512 + n];
  const unsigned short h = f2bf(w);
  dh[k] = h;
  dl[k] = f2bf(w - bf2f(h));
}

// ---------------------------------------------------------------------------
// Kernel 3: split-bf16 MFMA GEMM (unchanged from Round 3).
// ---------------------------------------------------------------------------
__global__ __launch_bounds__(256) void gemm_split_kernel(
    const unsigned short* __restrict__ A,    // M x 1024  [hi|lo]
    const unsigned short* __restrict__ Bh,   // Ncols x 512
    const unsigned short* __restrict__ Bl,   // Ncols x 512
    float* __restrict__ C0, float* __restrict__ C1, float* __restrict__ C2) {
  __shared__ unsigned short lds[8192];       // As 128x32 | Bs 128x32
  unsigned short* As = lds;
  unsigned short* Bs = lds + 4096;

  const int tid = threadIdx.x;
  const int wid = tid >> 6;
  const int lane = tid & 63;
  const int lm = lane & 15;
  const int kq = lane >> 4;
  const int wr = wid >> 1;
  const int wc = wid & 1;
  const int bm = blockIdx.y, bn = blockIdx.x;
  const int rowA0 = bm * 128;
  const int rowB0 = bn * 128;

  f32x4v acc[4][4];
  #pragma unroll
  for (int mi = 0; mi < 4; ++mi)
    #pragma unroll
    for (int ni = 0; ni < 4; ++ni) {
      f32x4v z = {0.f, 0.f, 0.f, 0.f};
      acc[mi][ni] = z;
    }

  auto kloop = [&](const unsigned short* __restrict__ Bsrc, int kmax) {
    for (int k0 = 0; k0 < kmax; k0 += 32) {
      #pragma unroll
      for (int i = 0; i < 2; ++i) {
        const int e = wid * 128 + i * 64 + lane;
        const int row = e >> 2;
        const int kc = (e & 3) << 3;
        const unsigned short* ga = A + (size_t)(rowA0 + row) * 1024 + k0 + kc;
        const unsigned short* gb = Bsrc + (size_t)(rowB0 + row) * 512 + (k0 & 511) + kc;
        __builtin_amdgcn_global_load_lds((gptr_t)ga,
            (lptr_t)(As + (size_t)(wid * 128 + i * 64) * 8), 16, 0, 0);
        __builtin_amdgcn_global_load_lds((gptr_t)gb,
            (lptr_t)(Bs + (size_t)(wid * 128 + i * 64) * 8), 16, 0, 0);
      }
      __syncthreads();
      i32x4 araw[4], braw[4];
      #pragma unroll
      for (int mi = 0; mi < 4; ++mi)
        araw[mi] = *(const i32x4*)(As + (size_t)(wr * 64 + mi * 16 + lm) * 32 + kq * 8);
      #pragma unroll
      for (int ni = 0; ni < 4; ++ni)
        braw[ni] = *(const i32x4*)(Bs + (size_t)(wc * 64 + ni * 16 + lm) * 32 + kq * 8);
      #pragma unroll
      for (int mi = 0; mi < 4; ++mi)
        #pragma unroll
        for (int ni = 0; ni < 4; ++ni)
          acc[mi][ni] = __builtin_amdgcn_mfma_f32_16x16x32_bf16(
              __builtin_bit_cast(bf16x8v, araw[mi]),
              __builtin_bit_cast(bf16x8v, braw[ni]), acc[mi][ni], 0, 0, 0);
      __syncthreads();
    }
  };
  kloop(Bh, 1024);
  kloop(Bl, 512);

  const int sel = bn >> 2;
  float* __restrict__ Cb = sel == 0 ? C0 : sel == 1 ? C1 : C2;
  const int r0 = bm * 128 + wr * 64;
  const int c0 = ((bn & 3) << 7) + wc * 64;
  #pragma unroll
  for (int mi = 0; mi < 4; ++mi)
    #pragma unroll
    for (int ni = 0; ni < 4; ++ni) {
      float* Cp = Cb + (size_t)(r0 + mi * 16 + kq * 4) * 512 + c0 + ni * 16 + lm;
      #pragma unroll
      for (int r = 0; r < 4; ++r) Cp[(size_t)r * 512] = acc[mi][ni][r];
    }
}

// ---------------------------------------------------------------------------
// Kernel 4: local attention — ONE WAVE PER QUERY, 8 lanes per head.
// lane = 8*h + s; each lane owns dims [lane*8, lane*8+8) of the 512-wide row.
// pe hoisted algebraically: q.(k_j + pe_j) = q.k_j + qw.rel_j + qb, where
// qw_c = sum_d q[h,d]*Wpos[c*128+d] (d<64) and qb = q.bpos[:64] — computed
// once per query. Per neighbor: full 2KB K-row coalesced load, 8 FMA/lane,
// 3-stage group reduce (xor 1,2,4). Output written as split-bf16 into the
// Wo GEMM's A buffer (16B/lane, coalesced).
// ---------------------------------------------------------------------------
__global__ __launch_bounds__(256) void attn_kernel(const float* __restrict__ Q,
                                                   const float* __restrict__ Kb,
                                                   const float* __restrict__ Vb,
                                                   const int* __restrict__ idx,
                                                   const float* __restrict__ pos,
                                                   const float* __restrict__ Wpos,
                                                   const float* __restrict__ bpos,
                                                   const float* __restrict__ temperature,
                                                   unsigned short* __restrict__ Aout,
                                                   int N) {
  const int qid = blockIdx.x * 4 + (threadIdx.x >> 6);   // 0 .. B*N-1
  const int lane = threadIdx.x & 63;
  const int s = lane & 7;                                // sub-lane in head
  const int b = qid / N;
  const int n = qid - b * N;

  const float inv_t = 1.0f / temperature[0];

  // q slice: 8 contiguous dims
  float q[8];
  *(float4*)&q[0] = *(const float4*)(Q + (size_t)qid * D_MODEL + lane * 8);
  *(float4*)&q[4] = *(const float4*)(Q + (size_t)qid * D_MODEL + lane * 8 + 4);

  // qw_c, qb: per-head 3-vector + scalar, reduced over the 8-lane group
  float wp[3][8], bp[8];
  #pragma unroll
  for (int c = 0; c < 3; ++c) {
    *(float4*)&wp[c][0] = *(const float4*)(Wpos + c * 128 + s * 8);
    *(float4*)&wp[c][4] = *(const float4*)(Wpos + c * 128 + s * 8 + 4);
  }
  *(float4*)&bp[0] = *(const float4*)(bpos + s * 8);
  *(float4*)&bp[4] = *(const float4*)(bpos + s * 8 + 4);
  float qw0 = 0.f, qw1 = 0.f, qw2 = 0.f, qb = 0.f;
  #pragma unroll
  for (int j = 0; j < 8; ++j) {
    qw0 += q[j] * wp[0][j];
    qw1 += q[j] * wp[1][j];
    qw2 += q[j] * wp[2][j];
    qb  += q[j] * bp[j];
  }
  #pragma unroll
  for (int off = 1; off < 8; off <<= 1) {
    qw0 += __shfl_xor(qw0, off, 64);
    qw1 += __shfl_xor(qw1, off, 64);
    qw2 += __shfl_xor(qw2, off, 64);
    qb  += __shfl_xor(qb, off, 64);
  }

  const float px = pos[(size_t)qid * 3 + 0];
  const float py = pos[(size_t)qid * 3 + 1];
  const float pz = pos[(size_t)qid * 3 + 2];
  const int* ip = idx + (size_t)qid * KNB;
  int nb[KNB];
  #pragma unroll
  for (int k = 0; k < KNB; ++k) nb[k] = ip[k];

  // ---- scores ----
  float sc[KNB];
  #pragma unroll
  for (int k = 0; k < KNB; ++k) {
    const int j = nb[k];
    const size_t jg = (size_t)(b * N + j);
    const float* kr = Kb + jg * D_MODEL + lane * 8;
    float kk[8];
    *(float4*)&kk[0] = *(const float4*)(kr);
    *(float4*)&kk[4] = *(const float4*)(kr + 4);
    float p = 0.f;
    #pragma unroll
    for (int j2 = 0; j2 < 8; ++j2) p += q[j2] * kk[j2];
    #pragma unroll
    for (int off = 1; off < 8; off <<= 1) p += __shfl_xor(p, off, 64);
    const float rx = px - pos[jg * 3 + 0];
    const float ry = py - pos[jg * 3 + 1];
    const float rz = pz - pos[jg * 3 + 2];
    sc[k] = (p + qw0 * rx + qw1 * ry + qw2 * rz + qb) * inv_t;
  }

  // ---- softmax over 16 (replicated within 8-lane group) ----
  float m = sc[0];
  #pragma unroll
  for (int k = 1; k < KNB; ++k) m = fmaxf(m, sc[k]);
  float ssum = 0.f;
  #pragma unroll
  for (int k = 0; k < KNB; ++k) { sc[k] = expf(sc[k] - m); ssum += sc[k]; }
  const float inv_s = 1.f / ssum;

  // ---- weighted V accumulation ----
  float acc[8];
  #pragma unroll
  for (int j = 0; j < 8; ++j) acc[j] = 0.f;
  #pragma unroll
  for (int k = 0; k < KNB; ++k) {
    const size_t jg = (size_t)(b * N + nb[k]);
    const float* vr = Vb + jg * D_MODEL + lane * 8;
    float vv[8];
    *(float4*)&vv[0] = *(const float4*)(vr);
    *(float4*)&vv[4] = *(const float4*)(vr + 4);
    const float wk = sc[k];
    #pragma unroll
    for (int j = 0; j < 8; ++j) acc[j] += wk * vv[j];
  }

  // ---- write split bf16 straight into the Wo GEMM's A buffer ----
  ushort4 hi0, hi1, lo0, lo1;
  unsigned short* oh = Aout + (size_t)qid * 1024 + lane * 8;
  unsigned short* ol = oh + 512;
  float a0 = acc[0] * inv_s, a1 = acc[1] * inv_s, a2 = acc[2] * inv_s, a3 = acc[3] * inv_s;
  float a4 = acc[4] * inv_s, a5 = acc[5] * inv_s, a6 = acc[6] * inv_s, a7 = acc[7] * inv_s;
  hi0.x = f2bf(a0); lo0.x = f2bf(a0 - bf2f(hi0.x));
  hi0.y = f2bf(a1); lo0.y = f2bf(a1 - bf2f(hi0.y));
  hi0.z = f2bf(a2); lo0.z = f2bf(a2 - bf2f(hi0.z));
  hi0.w = f2bf(a3); lo0.w = f2bf(a3 - bf2f(hi0.w));
  hi1.x = f2bf(a4); lo1.x = f2bf(a4 - bf2f(hi1.x));
  hi1.y = f2bf(a5); lo1.y = f2bf(a5 - bf2f(hi1.y));
  hi1.z = f2bf(a6); lo1.z = f2bf(a6 - bf2f(hi1.z));
  hi1.w = f2bf(a7); lo1.w = f2bf(a7 - bf2f(hi1.w));
  *(ushort4*)(oh) = hi0;
  *(ushort4*)(oh + 4) = hi1;
  *(ushort4*)(ol) = lo0;
  *(ushort4*)(ol + 4) = lo1;
}

// ---------------------------------------------------------------------------
// Kernel 5: out = LayerNorm(proj + bo + features) * gamma + beta
// ---------------------------------------------------------------------------
__global__ __launch_bounds__(256) void ln_kernel(const float* __restrict__ proj,
                                                 const float* __restrict__ feat,
                                                 const float* __restrict__ bo,
                                                 const float* __restrict__ gamma,
                                                 const float* __restrict__ beta,
                                                 float* __restrict__ out) {
  const int row = blockIdx.x * 4 + (threadIdx.x >> 6);
  const int lane = threadIdx.x & 63;
  const float* pr = proj + (size_t)row * D_MODEL;
  const float* fr = feat + (size_t)row * D_MODEL;

  float x[8];
  #pragma unroll
  for (int u = 0; u < 2; ++u) {
    const int c = u * 256 + lane * 4;
    const float4 p = *(const float4*)(pr + c);
    const float4 f = *(const float4*)(fr + c);
    const float4 bb = *(const float4*)(bo + c);
    x[u * 4 + 0] = p.x + bb.x + f.x;
    x[u * 4 + 1] = p.y + bb.y + f.y;
    x[u * 4 + 2] = p.z + bb.z + f.z;
    x[u * 4 + 3] = p.w + bb.w + f.w;
  }
  float sum = 0.f, sumsq = 0.f;
  #pragma unroll
  for (int i = 0; i < 8; ++i) { sum += x[i]; sumsq += x[i] * x[i]; }
  sum = wave_reduce_sum(sum);
  sumsq = wave_reduce_sum(sumsq);
  const float mu = sum * (1.f / D_MODEL);
  const float var = sumsq * (1.f / D_MODEL) - mu * mu;
  const float rstd = rsqrtf(var + LN_EPS);

  #pragma unroll
  for (int u = 0; u < 2; ++u) {
    const int c = u * 256 + lane * 4;
    const float4 g = *(const float4*)(gamma + c);
    const float4 bt = *(const float4*)(beta + c);
    float4 o;
    o.x = (x[u * 4 + 0] - mu) * rstd * g.x + bt.x;
    o.y = (x[u * 4 + 1] - mu) * rstd * g.y + bt.y;
    o.z = (x[u * 4 + 2] - mu) * rstd * g.z + bt.z;
    o.w = (x[u * 4 + 3] - mu) * rstd * g.w + bt.w;
    *(float4*)(out + (size_t)row * D_MODEL + c) = o;
  }
}

// ---------------------------------------------------------------------------
extern "C" void kernel_launch(void* const* d_in, const int* in_sizes, int n_in,
                              void* d_out, int out_size, void* d_ws, size_t ws_size,
                              hipStream_t stream) {
  const float* positions = (const float*)d_in[0];
  const float* features  = (const float*)d_in[1];
  const float* Wq   = (const float*)d_in[3];
  const float* Wk   = (const float*)d_in[4];
  const float* Wv   = (const float*)d_in[5];
  const float* Wo   = (const float*)d_in[6];
  const float* bo   = (const float*)d_in[7];
  const float* Wpos = (const float*)d_in[8];
  const float* bpos = (const float*)d_in[9];
  const float* temp = (const float*)d_in[10];
  const float* gamma = (const float*)d_in[11];
  const float* beta  = (const float*)d_in[12];

  const int B = 2, N = 4096;
  const int BN = B * N;

  char* w = (char*)d_ws;
  float4* posf4 = (float4*)w;              w += (size_t)BN * sizeof(float4);
  int*    idxb  = (int*)w;                 w += (size_t)BN * KNB * sizeof(int);
  unsigned short* Abuf = (unsigned short*)w; w += (size_t)BN * 1024 * 2;
  unsigned short* BhQKV = (unsigned short*)w; w += (size_t)1536 * 512 * 2;
  unsigned short* BlQKV = (unsigned short*)w; w += (size_t)1536 * 512 * 2;
  unsigned short* BhO = (unsigned short*)w;   w += (size_t)512 * 512 * 2;
  unsigned short* BlO = (unsigned short*)w;   w += (size_t)512 * 512 * 2;
  float* Qb   = (float*)w;                 w += (size_t)BN * D_MODEL * sizeof(float);
  float* Kbuf = (float*)w;                 w += (size_t)BN * D_MODEL * sizeof(float);
  float* Vbuf = (float*)d_out;
  float* projb = Kbuf;

  pad_pos_kernel<<<(BN + 255) / 256, 256, 0, stream>>>(positions, posf4, BN);
  knn_kernel<<<BN, 64, 0, stream>>>(posf4, idxb, N);

  conv_feat_kernel<<<(BN * D_MODEL / 4 + 255) / 256, 256, 0, stream>>>(
      features, Abuf, BN * D_MODEL / 4);
  conv_w_kernel<<<4096, 256, 0, stream>>>(Wq, Wk, Wv, Wo, BhQKV, BlQKV, BhO, BlO);

  gemm_split_kernel<<<dim3(12, BN / 128), 256, 0, stream>>>(
      Abuf, BhQKV, BlQKV, Qb, Kbuf, Vbuf);

  attn_kernel<<<BN / 4, 256, 0, stream>>>(Qb, Kbuf, Vbuf, idxb,
                                          positions, Wpos, bpos,
                                          temp, Abuf, N);

  gemm_split_kernel<<<dim3(4, BN / 128), 256, 0, stream>>>(
      Abuf, BhO, BlO, projb, projb, projb);

  ln_kernel<<<BN / 4, 256, 0, stream>>>(projb, features, bo, gamma, beta,
                                        (float*)d_out);
}